// Round 8
// baseline (83.915 us; speedup 1.0000x reference)
//
#include <hip/hip_runtime.h>
#include <hip/hip_bf16.h>
#include <cstdint>

// x: [8,8192,512] f32 -> LN over E=512 -> h=[16384,2048] bf16 (row-major flatten)
// W: [2048,512] f32, b: [512]; out = gelu(h @ W' + b'),
// W' = gamma-folded W (bf16, transposed), b' = b + beta @ W.
#define XROWS   65536
#define E       512
#define MROWS   16384
#define KDIM    2048
#define NDIM    512
#define NT      32        // K-steps of 64

typedef __attribute__((ext_vector_type(4))) float f32x4;
typedef __attribute__((ext_vector_type(8))) unsigned short u16x8;
typedef __attribute__((ext_vector_type(8))) __bf16 bf16x8;

__device__ __forceinline__ unsigned short f2bf(float f) {
  unsigned u = __builtin_bit_cast(unsigned, f);
  u += 0x7FFFu + ((u >> 16) & 1u);   // round-to-nearest-even
  return (unsigned short)(u >> 16);
}

typedef const __attribute__((address_space(1))) unsigned char ga_u8;
typedef __attribute__((address_space(3))) unsigned char ls_u8;
__device__ __forceinline__ void gload16(const void* g, void* l) {
  __builtin_amdgcn_global_load_lds((ga_u8*)g, (ls_u8*)l, 16, 0, 0);
}

// fast gelu (tanh form), |err vs erf form| <= ~3e-3 << 0.094 threshold
__device__ __forceinline__ float gelu_f(float v) {
  float p = v * (2.3022083f + 0.1029432f * (v * v));
  p = fminf(p, 80.0f);
  const float Ee = exp2f(p);
  return v * Ee * __builtin_amdgcn_rcpf(Ee + 1.0f);
}

// ---------------------------------------------------------------------------
// W [2048][512] f32 -> WT [512][2048] bf16, gamma folded in:
//   WT[n][k] = bf16(gamma[k % 512] * W[k][n])
// ---------------------------------------------------------------------------
__global__ __launch_bounds__(256) void wt_kernel(const float* __restrict__ W,
                                                 const float* __restrict__ gamma,
                                                 unsigned short* __restrict__ WT) {
  __shared__ float tile[64][68];
  const int t  = threadIdx.x;
  const int bk = blockIdx.x >> 3;
  const int bn = blockIdx.x & 7;
  const int c4 = (t & 15) * 4;
#pragma unroll
  for (int i = 0; i < 4; ++i) {
    const int r = (t >> 4) + i * 16;
    const f32x4 v = *(const f32x4*)&W[(size_t)(bk * 64 + r) * NDIM + bn * 64 + c4];
    tile[r][c4 + 0] = v.x; tile[r][c4 + 1] = v.y;
    tile[r][c4 + 2] = v.z; tile[r][c4 + 3] = v.w;
  }
  __syncthreads();
#pragma unroll
  for (int j = 0; j < 2; ++j) {
    const int n  = j * 32 + (t >> 3);
    const int kb = (t & 7) * 8;
    const int kg0 = (bk & 7) * 64 + kb;
    const f32x4 g0 = *(const f32x4*)(gamma + kg0);
    const f32x4 g1 = *(const f32x4*)(gamma + kg0 + 4);
    const float gg[8] = {g0.x, g0.y, g0.z, g0.w, g1.x, g1.y, g1.z, g1.w};
    u16x8 o;
#pragma unroll
    for (int q = 0; q < 8; ++q) o[q] = f2bf(gg[q] * tile[kb + q][n]);
    *(u16x8*)&WT[(size_t)(bn * 64 + n) * KDIM + bk * 64 + kb] = o;
  }
}

// ---------------------------------------------------------------------------
// beta fold: partial[32][512] then reduce + b.
// ---------------------------------------------------------------------------
__global__ __launch_bounds__(256) void kbias1(const float* __restrict__ W,
                                              const float* __restrict__ beta,
                                              float* __restrict__ partial) {
  const int bk = blockIdx.x, tid = threadIdx.x;
  float a0 = 0.f, a1 = 0.f;
  for (int k = 0; k < 64; ++k) {
    const int kg = bk * 64 + k;
    const float be = beta[kg & (E - 1)];
    a0 += be * W[(size_t)kg * NDIM + tid];
    a1 += be * W[(size_t)kg * NDIM + 256 + tid];
  }
  partial[bk * NDIM + tid] = a0;
  partial[bk * NDIM + 256 + tid] = a1;
}

__global__ __launch_bounds__(256) void kbias2(const float* __restrict__ b,
                                              const float* __restrict__ partial,
                                              float* __restrict__ biasf) {
  const int c = blockIdx.x * 256 + threadIdx.x;
  float s = b[c];
  for (int j = 0; j < 32; ++j) s += partial[j * NDIM + c];
  biasf[c] = s;
}

// ---------------------------------------------------------------------------
// LayerNorm: one wave per x-row of 512 f32 -> bf16 h (gamma/beta folded out).
// ---------------------------------------------------------------------------
__global__ __launch_bounds__(256, 4) void ln_kernel(const float* __restrict__ x,
                                                    unsigned short* __restrict__ h) {
  const int w = threadIdx.x >> 6, l = threadIdx.x & 63;
  const size_t row = (size_t)blockIdx.x * 4 + w;
  const float* xr = x + row * E + l * 8;
  const f32x4 v0 = *(const f32x4*)xr;
  const f32x4 v1 = *(const f32x4*)(xr + 4);
  float xv[8] = {v0.x, v0.y, v0.z, v0.w, v1.x, v1.y, v1.z, v1.w};
  float s = 0.f, q = 0.f;
#pragma unroll
  for (int j = 0; j < 8; ++j) { s += xv[j]; q += xv[j] * xv[j]; }
#pragma unroll
  for (int off = 32; off > 0; off >>= 1) {
    s += __shfl_xor(s, off);
    q += __shfl_xor(q, off);
  }
  const float mean = s * (1.0f / E);
  const float var  = q * (1.0f / E) - mean * mean;
  const float rstd = rsqrtf(var + 1e-6f);
  const float nm   = -mean * rstd;
  u16x8 o;
#pragma unroll
  for (int j = 0; j < 8; ++j) o[j] = f2bf(xv[j] * rstd + nm);
  *(u16x8*)(h + row * E + l * 8) = o;
}

// ---------------------------------------------------------------------------
// GEMM: h[16384 x 2048 bf16] x WT[512 x 2048 bf16] -> out f32, + bias+gelu.
// 128x128 tile, BK=64, 4 waves (2x2), DOUBLE-buffered 2x32KB LDS,
// COUNTED-vmcnt pipeline (T4): iter t issues stage(t+1) -> buf^1 FIRST, then
// waits vmcnt(8) (= stage(t) landed; stage(t+1)'s 8 loads stay in flight
// across both barriers with a full iteration of MFMA covering their latency).
// No vmcnt(0) in the main loop. T5 setprio around MFMA clusters.
// T1 XCD-chunked swizzle (512 = 8x64, bijective). T2 XOR swizzle on LDS.
// ---------------------------------------------------------------------------
#define VMCNT(n) asm volatile("s_waitcnt vmcnt(" #n ")" ::: "memory")

__global__ __launch_bounds__(256, 2) void gemm_kernel(const unsigned short* __restrict__ A,
                                                      const unsigned short* __restrict__ Bt,
                                                      const float* __restrict__ biasf,
                                                      float* __restrict__ out) {
  __shared__ char smem[2 * 32768];   // per buf: A 16KB @0, B 16KB @16384
  const int tid = threadIdx.x;
  const int l = tid & 63, w = tid >> 6;
  const int l7 = l & 7, l15 = l & 15, lhi = l >> 4;
  const int wr = w >> 1, wc = w & 1;

  // XCD chunking: grid 512 = 8 XCDs x 64; bn in low 2 bits of wg
  const int wg = ((blockIdx.x & 7) << 6) | (blockIdx.x >> 3);
  const int bn = wg & 3;
  const int bm = wg >> 2;
  const size_t arow0 = (size_t)bm * 128;
  const int    brow0 = bn * 128;

  // staging: thread covers rows {i*32 + w*8 + (l>>3)}, swizzled source col
  const int srow = w * 8 + (l >> 3);
  const int swz  = (l7 * 16) ^ ((l >> 3) << 4);
  const char* gA = (const char*)A  + ((size_t)(arow0 + srow) * KDIM) * 2 + swz;
  const char* gB = (const char*)Bt + ((size_t)(brow0 + srow) * KDIM) * 2 + swz;

  auto stage = [&](int t) {   // exactly 8 gload_lds (the only loop VMEM ops)
    char* base = smem + (t & 1) * 32768;
    const char* pa = gA + (size_t)t * 128;
    const char* pb = gB + (size_t)t * 128;
#pragma unroll
    for (int i = 0; i < 4; ++i) {
      gload16(pa + (size_t)i * 32 * KDIM * 2, base + (i * 32 + w * 8) * 128);
      gload16(pb + (size_t)i * 32 * KDIM * 2, base + 16384 + (i * 32 + w * 8) * 128);
    }
  };

  f32x4 acc[4][4];
#pragma unroll
  for (int m = 0; m < 4; ++m)
#pragma unroll
    for (int n = 0; n < 4; ++n) acc[m][n] = (f32x4){0.f, 0.f, 0.f, 0.f};

  // frag-read swizzled k-byte for kk=0; kk=1 flips bit 6 (outside swizzle)
  const int cs0 = (lhi * 16) ^ (l7 * 16);

  stage(0);                          // 8 loads in flight

  for (int t = 0; t < NT; ++t) {
    // issue next tile BEFORE waiting: its 8 loads ride across the barriers
    if (t + 1 < NT) {
      stage(t + 1);                  // -> buf[~t] (read-released last iter)
      VMCNT(8);                      // stage(t) landed; stage(t+1) in flight
    } else {
      VMCNT(0);                      // tail: only stage(NT-1) outstanding
    }
    __builtin_amdgcn_s_barrier();    // all waves' stage(t) visible

    const char* Ab = smem + (t & 1) * 32768;
    const char* Bb = Ab + 16384;
#pragma unroll
    for (int kk = 0; kk < 2; ++kk) {
      const int co = cs0 ^ (kk * 64);
      bf16x8 av[4], bv[4];
#pragma unroll
      for (int m = 0; m < 4; ++m)
        av[m] = *(const bf16x8*)(Ab + (wr * 64 + m * 16 + l15) * 128 + co);
#pragma unroll
      for (int n = 0; n < 4; ++n)
        bv[n] = *(const bf16x8*)(Bb + (wc * 64 + n * 16 + l15) * 128 + co);
      __builtin_amdgcn_s_setprio(1);
#pragma unroll
      for (int m = 0; m < 4; ++m)
#pragma unroll
        for (int n = 0; n < 4; ++n)
          acc[m][n] = __builtin_amdgcn_mfma_f32_16x16x32_bf16(av[m], bv[n],
                                                              acc[m][n], 0, 0, 0);
      __builtin_amdgcn_s_setprio(0);
    }
    asm volatile("s_waitcnt lgkmcnt(0)" ::: "memory");
    __builtin_amdgcn_s_barrier();    // buf[t&1] read-released for stage(t+2)
  }

  // epilogue: bias + fast gelu. C/D layout (m89): col = l&15, row = (l>>4)*4+reg
#pragma unroll
  for (int n = 0; n < 4; ++n) {
    const int col = brow0 + wc * 64 + n * 16 + l15;
    const float bb = biasf[col];
#pragma unroll
    for (int m = 0; m < 4; ++m) {
      const size_t rbase = arow0 + wr * 64 + m * 16 + lhi * 4;
#pragma unroll
      for (int r = 0; r < 4; ++r) {
        const float v = acc[m][n][r] + bb;
        out[(rbase + r) * NDIM + col] = gelu_f(v);
      }
    }
  }
}

// ---------------------------------------------------------------------------
extern "C" void kernel_launch(void* const* d_in, const int* in_sizes, int n_in,
                              void* d_out, int out_size, void* d_ws, size_t ws_size,
                              hipStream_t stream) {
  const float* x     = (const float*)d_in[0];
  const float* gamma = (const float*)d_in[1];
  const float* beta  = (const float*)d_in[2];
  const float* W     = (const float*)d_in[3];
  const float* b     = (const float*)d_in[4];
  float* out = (float*)d_out;

  // ws layout: WT 2MB | h 64MB | partial 64KB | biasf 2KB
  char* p = (char*)d_ws;
  unsigned short* WT = (unsigned short*)p;            p += (size_t)NDIM * KDIM * 2;
  unsigned short* h  = (unsigned short*)p;            p += (size_t)MROWS * KDIM * 2;
  float* partial     = (float*)p;                     p += (size_t)32 * NDIM * 4;
  float* biasf       = (float*)p;

  wt_kernel<<<256, 256, 0, stream>>>(W, gamma, WT);
  kbias1<<<32, 256, 0, stream>>>(W, beta, partial);
  kbias2<<<2, 256, 0, stream>>>(b, partial, biasf);
  ln_kernel<<<XROWS / 4, 256, 0, stream>>>(x, h);
  gemm_kernel<<<(MROWS / 128) * 4, 256, 0, stream>>>(h, WT, biasf, out);
}